// Round 2
// baseline (8704.379 us; speedup 1.0000x reference)
//
#include <hip/hip_runtime.h>

#define B_ 64
#define S_ 128
#define H_ 512
#define E_ 512
#define V_ 32000
#define T_ 30
#define KX_ 1536   // E + 2H  (GRU input  [emb|ctx])
#define KF_ 2048   // E + 3H  (fc  input  [emb|h|ctx])

typedef float f32x4 __attribute__((ext_vector_type(4)));
typedef short s16x8 __attribute__((ext_vector_type(8)));
typedef short s16x4 __attribute__((ext_vector_type(4)));

__device__ __forceinline__ short f2bf(float f) {
  union { float f; unsigned u; } v; v.f = f;
  unsigned r = v.u + 0x7fffu + ((v.u >> 16) & 1u);
  return (short)(r >> 16);
}
__device__ __forceinline__ float bf2f(short s) {
  union { unsigned u; float f; } v; v.u = ((unsigned)(unsigned short)s) << 16;
  return v.f;
}
__device__ __forceinline__ f32x4 mfma16(s16x8 a, s16x8 b, f32x4 c) {
  return __builtin_amdgcn_mfma_f32_16x16x32_bf16(a, b, c, 0, 0, 0);
}

// -------- software grid barrier (monotonic count; 256 co-resident blocks)
__device__ __forceinline__ void gbar(unsigned* cnt, unsigned target) {
  __threadfence();                 // flush this block's writes device-wide
  __syncthreads();
  if (threadIdx.x == 0) {
    atomicAdd(cnt, 1u);
    while (atomicAdd(cnt, 0u) < target) __builtin_amdgcn_s_sleep(1);
  }
  __syncthreads();
  __threadfence();                 // see other blocks' released writes
}

// ---------------------------------------------------------------- cvt fp32->bf16
__global__ __launch_bounds__(256) void cvt_bf16_kernel(const float* __restrict__ src,
                                                       short* __restrict__ dst, int n4) {
  int i = blockIdx.x * 256 + threadIdx.x;
  if (i >= n4) return;
  f32x4 v = *(const f32x4*)(src + (size_t)i * 4);
  s16x4 o;
  o[0] = f2bf(v[0]); o[1] = f2bf(v[1]); o[2] = f2bf(v[2]); o[3] = f2bf(v[3]);
  *(s16x4*)(dst + (size_t)i * 4) = o;
}

// ---------------------------------------------------------------- init hidden + barrier reset
__global__ __launch_bounds__(256) void init_kernel(const float* __restrict__ ehid,
                                                   float* __restrict__ hidden,
                                                   short* __restrict__ xg,
                                                   unsigned* __restrict__ bar) {
  int i = blockIdx.x * 256 + threadIdx.x;   // 32768
  if (blockIdx.x == 0 && threadIdx.x < 64) bar[threadIdx.x] = 0u;
  float h = ehid[i];
  hidden[i] = h;
  int b = i >> 9, hh = i & 511;
  xg[b * 2048 + 1536 + hh] = f2bf(h);
}

// ---------------------------------------------------------------- enc_ua = enc @ ua^T  (M=8192,N=512,K=1024) -> bf16 out
__global__ __launch_bounds__(256) void enc_ua_kernel(const float* __restrict__ enc,
                                                     const float* __restrict__ ua,
                                                     short* __restrict__ enc_ua) {
  __shared__ short alds[64 * 264];
  int tid = threadIdx.x;
  int wv = tid >> 6, lane = tid & 63;
  int q = lane >> 4, ml = lane & 15;
  int m0 = blockIdx.x * 64;                 // 128 m-blocks
  int n0 = blockIdx.y * 128 + wv * 32;      // 4 n-blocks
  f32x4 acc[4][2];
  f32x4 zz = {0.f, 0.f, 0.f, 0.f};
#pragma unroll
  for (int a = 0; a < 4; a++) { acc[a][0] = zz; acc[a][1] = zz; }

  for (int kc = 0; kc < 4; kc++) {          // K chunks of 256
    __syncthreads();
    for (int i = tid; i < 4096; i += 256) { // 64 rows x 64 float4
      int m = i >> 6, kk = (i & 63) << 2;
      f32x4 v = *(const f32x4*)(enc + (size_t)(m0 + m) * 1024 + kc * 256 + kk);
      s16x4 o;
      o[0] = f2bf(v[0]); o[1] = f2bf(v[1]); o[2] = f2bf(v[2]); o[3] = f2bf(v[3]);
      *(s16x4*)(&alds[m * 264 + kk]) = o;
    }
    __syncthreads();
#pragma unroll
    for (int kt = 0; kt < 8; kt++) {
      int k = kt * 32 + q * 8;
      int gk = kc * 256 + k;
      s16x8 bf[2];
#pragma unroll
      for (int nf = 0; nf < 2; nf++) {
        const float* bp = ua + (size_t)(n0 + nf * 16 + ml) * 1024 + gk;
        f32x4 b0 = *(const f32x4*)bp, b1 = *(const f32x4*)(bp + 4);
        s16x8 tt;
        tt[0] = f2bf(b0[0]); tt[1] = f2bf(b0[1]); tt[2] = f2bf(b0[2]); tt[3] = f2bf(b0[3]);
        tt[4] = f2bf(b1[0]); tt[5] = f2bf(b1[1]); tt[6] = f2bf(b1[2]); tt[7] = f2bf(b1[3]);
        bf[nf] = tt;
      }
#pragma unroll
      for (int mt = 0; mt < 4; mt++) {
        s16x8 af = *(const s16x8*)(&alds[(mt * 16 + ml) * 264 + k]);
        acc[mt][0] = mfma16(af, bf[0], acc[mt][0]);
        acc[mt][1] = mfma16(af, bf[1], acc[mt][1]);
      }
    }
  }
#pragma unroll
  for (int nf = 0; nf < 2; nf++) {
    int n = n0 + nf * 16 + ml;
#pragma unroll
    for (int mt = 0; mt < 4; mt++)
#pragma unroll
      for (int r = 0; r < 4; r++) {
        int m = m0 + mt * 16 + q * 4 + r;
        enc_ua[(size_t)m * 512 + n] = f2bf(acc[mt][nf][r]);
      }
  }
}

// ---------------------------------------------------------------- all-step embedding gather (teacher forcing)
__global__ __launch_bounds__(256) void emb_gather_kernel(const float* __restrict__ emb,
                                                         const int* __restrict__ tgt,
                                                         short* __restrict__ emb_all) {
  int b = blockIdx.x, t = blockIdx.y, tid = threadIdx.x;
  int tok = (t == 0) ? 2 : tgt[b * 30 + (t - 1)];
  const float* src = emb + (size_t)tok * 512;
  short* dst = emb_all + ((size_t)t * 64 + b) * 512;
  int h = tid * 2;
  float a0 = src[h], a1 = src[h + 1];
  dst[h] = f2bf(a0); dst[h + 1] = f2bf(a1);
}

// ================================================================ persistent decoder
struct PP {
  const short* fcwb; const float* fcwf; const float* fcb;
  const short* encb; const float* encf;
  const short* enc_ua; const short* wab;
  const short* wihb; const short* whhb;
  const float* bih; const float* bhh; const float* va;
  const short* emb_all;
  short* xg0; short* xg1; short* xf0; short* xf1;
  float* hid0; float* hid1; float* qv; float* out;
  unsigned* bar;
};

// -------- fc: 64-col tile of logits(tf) = xf(tf) @ fcw^T + fcb
template <bool PRE>
static __device__ void fc_tile(int tile, int tf, const short* __restrict__ xfb,
                               const PP& P, float* smf) {
  short* alds = (short*)smf;
  const int tid = threadIdx.x;
  const int wv = tid >> 6, lane = tid & 63;
  const int q = lane >> 4, ml = lane & 15;
  const int n = tile * 64 + wv * 16 + ml;
  const f32x4 zz = {0.f, 0.f, 0.f, 0.f};
  f32x4 acc[4];
  acc[0] = zz; acc[1] = zz; acc[2] = zz; acc[3] = zz;
  for (int kc = 0; kc < 8; kc++) {          // K chunks of 256
    __syncthreads();
    for (int i = tid; i < 2048; i += 256) { // 64 rows x 32 x (8 bf16)
      int m = i >> 5, kk = (i & 31) << 3;
      *(s16x8*)(&alds[m * 264 + kk]) = *(const s16x8*)(xfb + (size_t)m * 2048 + kc * 256 + kk);
    }
    __syncthreads();
#pragma unroll
    for (int kt = 0; kt < 8; kt++) {
      int k = kt * 32 + q * 8;
      int gk = kc * 256 + k;
      s16x8 bf;
      if (PRE) {
        bf = *(const s16x8*)(P.fcwb + (size_t)n * 2048 + gk);
      } else {
        const float* p0 = P.fcwf + (size_t)n * 2048 + gk;
        f32x4 a0 = *(const f32x4*)p0, a1 = *(const f32x4*)(p0 + 4);
        bf[0] = f2bf(a0[0]); bf[1] = f2bf(a0[1]); bf[2] = f2bf(a0[2]); bf[3] = f2bf(a0[3]);
        bf[4] = f2bf(a1[0]); bf[5] = f2bf(a1[1]); bf[6] = f2bf(a1[2]); bf[7] = f2bf(a1[3]);
      }
#pragma unroll
      for (int mt = 0; mt < 4; mt++) {
        s16x8 af = *(const s16x8*)(&alds[(mt * 16 + ml) * 264 + k]);
        acc[mt] = mfma16(af, bf, acc[mt]);
      }
    }
  }
  float bias = P.fcb[n];
#pragma unroll
  for (int mt = 0; mt < 4; mt++)
#pragma unroll
    for (int r = 0; r < 4; r++) {
      int b = mt * 16 + q * 4 + r;
      P.out[((size_t)b * T_ + tf) * V_ + n] = acc[mt][r] + bias;
    }
}

// -------- per-row log_softmax over V
static __device__ void finalize_row(float* __restrict__ row, float* red) {
  const int tid = threadIdx.x;
  float mx = -3.4e38f;
  for (int i = tid; i < 8000; i += 256) {
    f32x4 v = *(const f32x4*)(row + (size_t)i * 4);
    mx = fmaxf(mx, fmaxf(fmaxf(v[0], v[1]), fmaxf(v[2], v[3])));
  }
  red[tid] = mx; __syncthreads();
  for (int st = 128; st >= 1; st >>= 1) {
    if (tid < st) red[tid] = fmaxf(red[tid], red[tid + st]);
    __syncthreads();
  }
  mx = red[0]; __syncthreads();
  float sm = 0.f;
  for (int i = tid; i < 8000; i += 256) {
    f32x4 v = *(const f32x4*)(row + (size_t)i * 4);
    sm += __expf(v[0] - mx) + __expf(v[1] - mx) + __expf(v[2] - mx) + __expf(v[3] - mx);
  }
  red[tid] = sm; __syncthreads();
  for (int st = 128; st >= 1; st >>= 1) {
    if (tid < st) red[tid] += red[tid + st];
    __syncthreads();
  }
  float lse = mx + __logf(red[0]);
  for (int i = tid; i < 8000; i += 256) {
    f32x4 v = *(const f32x4*)(row + (size_t)i * 4);
    v[0] -= lse; v[1] -= lse; v[2] -= lse; v[3] -= lse;
    *(f32x4*)(row + (size_t)i * 4) = v;
  }
}

// -------- fused attention for one batch row: scores -> softmax -> context
template <bool ENCB>
static __device__ void attn_block(int b, short* __restrict__ xg_cur, short* __restrict__ xf_cur,
                                  const PP& P, float* smf) {
  float* q_s = smf; float* va_s = smf + 512; float* p_s = smf + 1024; float* red = smf + 1152;
  const int tid = threadIdx.x;
  const int wv = tid >> 6, lane = tid & 63;
  for (int i = tid; i < 512; i += 256) {
    q_s[i] = P.qv[(size_t)b * 512 + i];
    va_s[i] = P.va[i];
  }
  __syncthreads();
  float qr[8], vr[8];
#pragma unroll
  for (int j = 0; j < 8; j++) { qr[j] = q_s[lane * 8 + j]; vr[j] = va_s[lane * 8 + j]; }
  for (int r = 0; r < 32; r++) {
    int s = wv * 32 + r;
    s16x8 e8 = *(const s16x8*)(P.enc_ua + ((size_t)b * 128 + s) * 512 + lane * 8);
    float a = 0.f;
#pragma unroll
    for (int j = 0; j < 8; j++) {
      float e = qr[j] + bf2f(e8[j]);
      float ex = __expf(2.f * e);
      a += (1.f - 2.f / (ex + 1.f)) * vr[j];
    }
#pragma unroll
    for (int off = 32; off > 0; off >>= 1) a += __shfl_down(a, off);
    if (lane == 0) p_s[s] = a;
  }
  __syncthreads();
  if (tid < 128) red[tid] = p_s[tid];
  __syncthreads();
  for (int st = 64; st >= 1; st >>= 1) {
    if (tid < st) red[tid] = fmaxf(red[tid], red[tid + st]);
    __syncthreads();
  }
  float mx = red[0]; __syncthreads();
  if (tid < 128) { float e = __expf(p_s[tid] - mx); p_s[tid] = e; red[tid] = e; }
  __syncthreads();
  for (int st = 64; st >= 1; st >>= 1) {
    if (tid < st) red[tid] += red[tid + st];
    __syncthreads();
  }
  float inv = 1.f / red[0]; __syncthreads();
  if (tid < 128) p_s[tid] *= inv;
  __syncthreads();
  int d4 = tid * 4;                         // [0,1024)
  f32x4 a = {0.f, 0.f, 0.f, 0.f};
  if (ENCB) {
    const short* ep = P.encb + (size_t)b * 128 * 1024 + d4;
#pragma unroll 4
    for (int s = 0; s < 128; s++) {
      s16x4 e = *(const s16x4*)(ep + (size_t)s * 1024);
      float p = p_s[s];
      a[0] += p * bf2f(e[0]); a[1] += p * bf2f(e[1]);
      a[2] += p * bf2f(e[2]); a[3] += p * bf2f(e[3]);
    }
  } else {
    const float* ep = P.encf + (size_t)b * 128 * 1024 + d4;
#pragma unroll 4
    for (int s = 0; s < 128; s++) {
      f32x4 e = *(const f32x4*)(ep + (size_t)s * 1024);
      float p = p_s[s];
      a[0] += p * e[0]; a[1] += p * e[1]; a[2] += p * e[2]; a[3] += p * e[3];
    }
  }
  s16x4 c4;
  c4[0] = f2bf(a[0]); c4[1] = f2bf(a[1]); c4[2] = f2bf(a[2]); c4[3] = f2bf(a[3]);
  *(s16x4*)(xg_cur + (size_t)b * 2048 + 512 + d4) = c4;
  *(s16x4*)(xf_cur + (size_t)b * 2048 + 1024 + d4) = c4;
}

// -------- fused GRU GEMM + gates for 16 h-columns (32 blocks cover H=512)
static __device__ void gru_block(int bid, const short* __restrict__ xg_cur,
                                 short* __restrict__ xg_nxt, short* __restrict__ xf_cur,
                                 const float* __restrict__ hid_cur, float* __restrict__ hid_nxt,
                                 const PP& P, float* gsm) {
  const int tid = threadIdx.x;
  const int wv = tid >> 6, lane = tid & 63;
  const int q = lane >> 4, ml = lane & 15;
  const int c16 = bid * 16;
  const int c = c16 + ml;
  const f32x4 zz = {0.f, 0.f, 0.f, 0.f};
  f32x4 acc[3][4];
#pragma unroll
  for (int g = 0; g < 3; g++)
#pragma unroll
    for (int mt = 0; mt < 4; mt++) acc[g][mt] = zz;

  if (wv < 3) {                             // gi partial: K slice [wv*512, wv*512+512)
    const int kbase = wv * 512;
    for (int kt = 0; kt < 16; kt++) {
      int k = kbase + kt * 32 + q * 8;
      s16x8 af[4];
#pragma unroll
      for (int mt = 0; mt < 4; mt++)
        af[mt] = *(const s16x8*)(xg_cur + (size_t)(mt * 16 + ml) * 2048 + k);
#pragma unroll
      for (int g = 0; g < 3; g++) {
        s16x8 bf = *(const s16x8*)(P.wihb + (size_t)(g * 512 + c) * 1536 + k);
#pragma unroll
        for (int mt = 0; mt < 4; mt++) acc[g][mt] = mfma16(af[mt], bf, acc[g][mt]);
      }
    }
  } else {                                  // gh full: K=512 over hidden slot
    for (int kt = 0; kt < 16; kt++) {
      int k = kt * 32 + q * 8;
      s16x8 af[4];
#pragma unroll
      for (int mt = 0; mt < 4; mt++)
        af[mt] = *(const s16x8*)(xg_cur + (size_t)(mt * 16 + ml) * 2048 + 1536 + k);
#pragma unroll
      for (int g = 0; g < 3; g++) {
        s16x8 bf = *(const s16x8*)(P.whhb + (size_t)(g * 512 + c) * 512 + k);
#pragma unroll
        for (int mt = 0; mt < 4; mt++) acc[g][mt] = mfma16(af[mt], bf, acc[g][mt]);
      }
    }
  }
#pragma unroll
  for (int g = 0; g < 3; g++)
#pragma unroll
    for (int mt = 0; mt < 4; mt++)
#pragma unroll
      for (int r = 0; r < 4; r++)
        gsm[((wv * 3 + g) * 64 + mt * 16 + q * 4 + r) * 17 + ml] = acc[g][mt][r];
  __syncthreads();
#pragma unroll
  for (int j = 0; j < 4; j++) {
    int o = tid + j * 256;                  // 64 b x 16 c
    int cc = o & 15, bb = o >> 4;
    int hcol = c16 + cc;
    float gi0 = gsm[((0) * 64 + bb) * 17 + cc] + gsm[((3) * 64 + bb) * 17 + cc] + gsm[((6) * 64 + bb) * 17 + cc];
    float gi1 = gsm[((1) * 64 + bb) * 17 + cc] + gsm[((4) * 64 + bb) * 17 + cc] + gsm[((7) * 64 + bb) * 17 + cc];
    float gi2 = gsm[((2) * 64 + bb) * 17 + cc] + gsm[((5) * 64 + bb) * 17 + cc] + gsm[((8) * 64 + bb) * 17 + cc];
    float gh0 = gsm[((9) * 64 + bb) * 17 + cc];
    float gh1 = gsm[((10) * 64 + bb) * 17 + cc];
    float gh2 = gsm[((11) * 64 + bb) * 17 + cc];
    float ir = gi0 + P.bih[hcol],         hr = gh0 + P.bhh[hcol];
    float iz = gi1 + P.bih[512 + hcol],   hz = gh1 + P.bhh[512 + hcol];
    float in_ = gi2 + P.bih[1024 + hcol], hn = gh2 + P.bhh[1024 + hcol];
    float r = 1.f / (1.f + __expf(-(ir + hr)));
    float z = 1.f / (1.f + __expf(-(iz + hz)));
    float nx = in_ + r * hn;
    float ex = __expf(2.f * nx);
    float n = 1.f - 2.f / (ex + 1.f);
    float hold = hid_cur[(size_t)bb * 512 + hcol];
    float hnew = (1.f - z) * n + z * hold;
    hid_nxt[(size_t)bb * 512 + hcol] = hnew;
    short hb = f2bf(hnew);
    xg_nxt[(size_t)bb * 2048 + 1536 + hcol] = hb;
    xf_cur[(size_t)bb * 2048 + 512 + hcol] = hb;
  }
}

template <bool PRE, bool ENCB>
__global__ __launch_bounds__(256) void decoder_persist(PP P) {
  __shared__ __align__(16) float sm[13872];  // 55.5 KB: max(fc stage 33.8K, gru 52.2K, attn 5K)
  const int bid = blockIdx.x, tid = threadIdx.x;
  const int wv = tid >> 6, lane = tid & 63;
  const int q = lane >> 4, ml = lane & 15;
  const f32x4 zz = {0.f, 0.f, 0.f, 0.f};
  unsigned nb = 0;                           // barriers passed

  for (int t = 0; t < T_ + 2; t++) {
    short* xg_cur = (t & 1) ? P.xg1 : P.xg0;
    short* xg_nxt = (t & 1) ? P.xg0 : P.xg1;
    short* xf_cur = (t & 1) ? P.xf1 : P.xf0;
    const short* xf_prev = (t & 1) ? P.xf0 : P.xf1;   // xf of step t-1
    const float* hid_cur = (t & 1) ? P.hid1 : P.hid0;
    float* hid_nxt = (t & 1) ? P.hid0 : P.hid1;

    // ================= Phase 1: qv = h(t-1)@wa^T + emb(t) | finalize(t-2) | fc(t-1) [0,167)
    if (t < T_ && bid < 8) {
      int n = bid * 64 + wv * 16 + ml;
      f32x4 acc[4];
      acc[0] = zz; acc[1] = zz; acc[2] = zz; acc[3] = zz;
#pragma unroll
      for (int kt = 0; kt < 16; kt++) {
        int k = kt * 32 + q * 8;
        s16x8 bfrag = *(const s16x8*)(P.wab + (size_t)n * 512 + k);
#pragma unroll
        for (int mt = 0; mt < 4; mt++) {
          s16x8 af = *(const s16x8*)(xg_cur + (size_t)(mt * 16 + ml) * 2048 + 1536 + k);
          acc[mt] = mfma16(af, bfrag, acc[mt]);
        }
      }
#pragma unroll
      for (int mt = 0; mt < 4; mt++)
#pragma unroll
        for (int r = 0; r < 4; r++)
          P.qv[(size_t)(mt * 16 + q * 4 + r) * 512 + n] = acc[mt][r];
      // embedding copy into xg/xf (precomputed bf16, teacher-forced)
      int gid = bid * 256 + tid;            // [0,2048)
      int idx = gid * 16;                   // [0,32768)
      int b2 = idx >> 9, hh = idx & 511;
      const s16x8* src = (const s16x8*)(P.emb_all + (size_t)t * 32768 + idx);
      s16x8 e0 = src[0], e1 = src[1];
      *(s16x8*)(xg_cur + (size_t)b2 * 2048 + hh) = e0;
      *(s16x8*)(xg_cur + (size_t)b2 * 2048 + hh + 8) = e1;
      *(s16x8*)(xf_cur + (size_t)b2 * 2048 + hh) = e0;
      *(s16x8*)(xf_cur + (size_t)b2 * 2048 + hh + 8) = e1;
    } else if (t >= 2 && bid >= 8 && bid < 72) {
      finalize_row(P.out + ((size_t)(bid - 8) * T_ + (t - 2)) * V_, sm);
    } else if (t >= 1 && t <= T_ && bid >= 72 && bid < 239) {
      fc_tile<PRE>(bid - 72, t - 1, xf_prev, P, sm);
    }
    gbar(P.bar, ++nb * 256u);

    // ================= Phase 2: attention(t) | fc(t-1) [167,334)
    if (t < T_ && bid < 64) {
      attn_block<ENCB>(bid, xg_cur, xf_cur, P, sm);
    } else if (t >= 1 && t <= T_ && bid >= 64 && bid < 231) {
      fc_tile<PRE>(167 + bid - 64, t - 1, xf_prev, P, sm);
    }
    gbar(P.bar, ++nb * 256u);

    // ================= Phase 3: GRU+gates(t) | fc(t-1) [334,500)
    if (t < T_ && bid < 32) {
      gru_block(bid, xg_cur, xg_nxt, xf_cur, hid_cur, hid_nxt, P, sm);
    } else if (t >= 1 && t <= T_ && bid >= 32 && bid < 198) {
      fc_tile<PRE>(334 + bid - 32, t - 1, xf_prev, P, sm);
    }
    gbar(P.bar, ++nb * 256u);
  }
}

// ================================================================ host
extern "C" void kernel_launch(void* const* d_in, const int* in_sizes, int n_in,
                              void* d_out, int out_size, void* d_ws, size_t ws_size,
                              hipStream_t stream) {
  const float* enc  = (const float*)d_in[0];
  const float* ehid = (const float*)d_in[1];
  const int*   tgt  = (const int*)  d_in[2];
  const float* emb  = (const float*)d_in[3];
  const float* wa   = (const float*)d_in[4];
  const float* ua   = (const float*)d_in[5];
  const float* va   = (const float*)d_in[6];
  const float* wih  = (const float*)d_in[7];
  const float* whh  = (const float*)d_in[8];
  const float* bih  = (const float*)d_in[9];
  const float* bhh  = (const float*)d_in[10];
  const float* fcw  = (const float*)d_in[11];
  const float* fcb  = (const float*)d_in[12];
  float* out = (float*)d_out;

  const size_t SZ_FCWB = (size_t)V_ * KF_ * 2;        // 131 MB
  const size_t SZ_ENCB = (size_t)B_ * S_ * 1024 * 2;  // 16.8 MB
  char* ws = (char*)d_ws;
  size_t off = 0;
  auto take = [&](size_t bytes) -> char* {
    char* p = ws + off;
    off = (off + bytes + 255) & ~(size_t)255;
    return p;
  };
  size_t small_need;
  {
    size_t o = 0;
    auto sim = [&](size_t bb) { o = (o + bb + 255) & ~(size_t)255; };
    sim((size_t)B_ * S_ * H_ * 2);  // enc_ua bf16
    sim((size_t)3 * H_ * KX_ * 2);  // wihb
    sim((size_t)3 * H_ * H_ * 2);   // whhb
    sim((size_t)H_ * H_ * 2);       // wab
    sim((size_t)T_ * B_ * H_ * 2);  // emb_all
    sim((size_t)B_ * KF_ * 2);      // xg0
    sim((size_t)B_ * KF_ * 2);      // xg1
    sim((size_t)B_ * KF_ * 2);      // xf0
    sim((size_t)B_ * KF_ * 2);      // xf1
    sim((size_t)B_ * H_ * 4);       // hid0
    sim((size_t)B_ * H_ * 4);       // hid1
    sim((size_t)B_ * H_ * 4);       // qv
    sim(256);                       // barrier
    small_need = o;
  }
  bool PRE  = ws_size >= SZ_FCWB + small_need + 512;
  bool ENCB = ws_size >= SZ_FCWB + SZ_ENCB + small_need + 1024;

  short* fcwb = PRE ? (short*)take(SZ_FCWB) : nullptr;
  short* encb = ENCB ? (short*)take(SZ_ENCB) : nullptr;
  short* enc_ua  = (short*)take((size_t)B_ * S_ * H_ * 2);
  short* wihb    = (short*)take((size_t)3 * H_ * KX_ * 2);
  short* whhb    = (short*)take((size_t)3 * H_ * H_ * 2);
  short* wab     = (short*)take((size_t)H_ * H_ * 2);
  short* emb_all = (short*)take((size_t)T_ * B_ * H_ * 2);
  short* xg0     = (short*)take((size_t)B_ * KF_ * 2);
  short* xg1     = (short*)take((size_t)B_ * KF_ * 2);
  short* xf0     = (short*)take((size_t)B_ * KF_ * 2);
  short* xf1     = (short*)take((size_t)B_ * KF_ * 2);
  float* hid0    = (float*)take((size_t)B_ * H_ * 4);
  float* hid1    = (float*)take((size_t)B_ * H_ * 4);
  float* qv      = (float*)take((size_t)B_ * H_ * 4);
  unsigned* bar  = (unsigned*)take(256);

  if (PRE)
    cvt_bf16_kernel<<<(V_ * KF_ / 4 + 255) / 256, 256, 0, stream>>>(fcw, fcwb, V_ * KF_ / 4);
  if (ENCB)
    cvt_bf16_kernel<<<(B_ * S_ * 1024 / 4 + 255) / 256, 256, 0, stream>>>(enc, encb, B_ * S_ * 1024 / 4);
  cvt_bf16_kernel<<<(3 * H_ * KX_ / 4 + 255) / 256, 256, 0, stream>>>(wih, wihb, 3 * H_ * KX_ / 4);
  cvt_bf16_kernel<<<(3 * H_ * H_ / 4 + 255) / 256, 256, 0, stream>>>(whh, whhb, 3 * H_ * H_ / 4);
  cvt_bf16_kernel<<<(H_ * H_ / 4 + 255) / 256, 256, 0, stream>>>(wa, wab, H_ * H_ / 4);
  init_kernel<<<(B_ * H_) / 256, 256, 0, stream>>>(ehid, hid0, xg0, bar);
  enc_ua_kernel<<<dim3(128, 4), 256, 0, stream>>>(enc, ua, enc_ua);
  emb_gather_kernel<<<dim3(B_, T_), 256, 0, stream>>>(emb, tgt, emb_all);

  PP p;
  p.fcwb = fcwb; p.fcwf = fcw; p.fcb = fcb;
  p.encb = encb; p.encf = enc;
  p.enc_ua = enc_ua; p.wab = wab; p.wihb = wihb; p.whhb = whhb;
  p.bih = bih; p.bhh = bhh; p.va = va;
  p.emb_all = emb_all;
  p.xg0 = xg0; p.xg1 = xg1; p.xf0 = xf0; p.xf1 = xf1;
  p.hid0 = hid0; p.hid1 = hid1; p.qv = qv; p.out = out;
  p.bar = bar;

  if (PRE && ENCB)      decoder_persist<true, true><<<256, 256, 0, stream>>>(p);
  else if (PRE)         decoder_persist<true, false><<<256, 256, 0, stream>>>(p);
  else if (ENCB)        decoder_persist<false, true><<<256, 256, 0, stream>>>(p);
  else                  decoder_persist<false, false><<<256, 256, 0, stream>>>(p);
}

// Round 3
// 4076.492 us; speedup vs baseline: 2.1353x; 2.1353x over previous
//
#include <hip/hip_runtime.h>

#define B_ 64
#define S_ 128
#define H_ 512
#define E_ 512
#define V_ 32000
#define T_ 30
#define KX_ 1536   // E + 2H  (GRU input  [emb|ctx])
#define KF_ 2048   // E + 3H  (fc  input  [emb|h|ctx])

typedef float f32x4 __attribute__((ext_vector_type(4)));
typedef short s16x8 __attribute__((ext_vector_type(8)));
typedef short s16x4 __attribute__((ext_vector_type(4)));

__device__ __forceinline__ short f2bf(float f) {
  union { float f; unsigned u; } v; v.f = f;
  unsigned r = v.u + 0x7fffu + ((v.u >> 16) & 1u);
  return (short)(r >> 16);
}
__device__ __forceinline__ float bf2f(short s) {
  union { unsigned u; float f; } v; v.u = ((unsigned)(unsigned short)s) << 16;
  return v.f;
}
__device__ __forceinline__ f32x4 mfma16(s16x8 a, s16x8 b, f32x4 c) {
  return __builtin_amdgcn_mfma_f32_16x16x32_bf16(a, b, c, 0, 0, 0);
}

// ---------------------------------------------------------------- cvt fp32->bf16
__global__ __launch_bounds__(256) void cvt_bf16_kernel(const float* __restrict__ src,
                                                       short* __restrict__ dst, int n4) {
  int i = blockIdx.x * 256 + threadIdx.x;
  if (i >= n4) return;
  f32x4 v = *(const f32x4*)(src + (size_t)i * 4);
  s16x4 o;
  o[0] = f2bf(v[0]); o[1] = f2bf(v[1]); o[2] = f2bf(v[2]); o[3] = f2bf(v[3]);
  *(s16x4*)(dst + (size_t)i * 4) = o;
}

// ---------------------------------------------------------------- init hidden
__global__ __launch_bounds__(256) void init_kernel(const float* __restrict__ ehid,
                                                   float* __restrict__ hidden,
                                                   short* __restrict__ xg) {
  int i = blockIdx.x * 256 + threadIdx.x;   // 32768
  float h = ehid[i];
  hidden[i] = h;
  int b = i >> 9, hh = i & 511;
  xg[b * 2048 + 1536 + hh] = f2bf(h);
}

// ---------------------------------------------------------------- enc_ua = enc @ ua^T  (M=8192,N=512,K=1024) -> bf16 out
__global__ __launch_bounds__(256) void enc_ua_kernel(const float* __restrict__ enc,
                                                     const float* __restrict__ ua,
                                                     short* __restrict__ enc_ua) {
  __shared__ short alds[64 * 264];
  int tid = threadIdx.x;
  int wv = tid >> 6, lane = tid & 63;
  int q = lane >> 4, ml = lane & 15;
  int m0 = blockIdx.x * 64;                 // 128 m-blocks
  int n0 = blockIdx.y * 128 + wv * 32;      // 4 n-blocks
  f32x4 acc[4][2];
  f32x4 zz = {0.f, 0.f, 0.f, 0.f};
#pragma unroll
  for (int a = 0; a < 4; a++) { acc[a][0] = zz; acc[a][1] = zz; }

  for (int kc = 0; kc < 4; kc++) {          // K chunks of 256
    __syncthreads();
    for (int i = tid; i < 4096; i += 256) { // 64 rows x 64 float4
      int m = i >> 6, kk = (i & 63) << 2;
      f32x4 v = *(const f32x4*)(enc + (size_t)(m0 + m) * 1024 + kc * 256 + kk);
      s16x4 o;
      o[0] = f2bf(v[0]); o[1] = f2bf(v[1]); o[2] = f2bf(v[2]); o[3] = f2bf(v[3]);
      *(s16x4*)(&alds[m * 264 + kk]) = o;
    }
    __syncthreads();
#pragma unroll
    for (int kt = 0; kt < 8; kt++) {
      int k = kt * 32 + q * 8;
      int gk = kc * 256 + k;
      s16x8 bf[2];
#pragma unroll
      for (int nf = 0; nf < 2; nf++) {
        const float* bp = ua + (size_t)(n0 + nf * 16 + ml) * 1024 + gk;
        f32x4 b0 = *(const f32x4*)bp, b1 = *(const f32x4*)(bp + 4);
        s16x8 tt;
        tt[0] = f2bf(b0[0]); tt[1] = f2bf(b0[1]); tt[2] = f2bf(b0[2]); tt[3] = f2bf(b0[3]);
        tt[4] = f2bf(b1[0]); tt[5] = f2bf(b1[1]); tt[6] = f2bf(b1[2]); tt[7] = f2bf(b1[3]);
        bf[nf] = tt;
      }
#pragma unroll
      for (int mt = 0; mt < 4; mt++) {
        s16x8 af = *(const s16x8*)(&alds[(mt * 16 + ml) * 264 + k]);
        acc[mt][0] = mfma16(af, bf[0], acc[mt][0]);
        acc[mt][1] = mfma16(af, bf[1], acc[mt][1]);
      }
    }
  }
#pragma unroll
  for (int nf = 0; nf < 2; nf++) {
    int n = n0 + nf * 16 + ml;
#pragma unroll
    for (int mt = 0; mt < 4; mt++)
#pragma unroll
      for (int r = 0; r < 4; r++) {
        int m = m0 + mt * 16 + q * 4 + r;
        enc_ua[(size_t)m * 512 + n] = f2bf(acc[mt][nf][r]);
      }
  }
}

// ---------------------------------------------------------------- all-step embedding gather (teacher forcing)
__global__ __launch_bounds__(256) void emb_gather_kernel(const float* __restrict__ emb,
                                                         const int* __restrict__ tgt,
                                                         short* __restrict__ emb_all) {
  int b = blockIdx.x, t = blockIdx.y, tid = threadIdx.x;
  int tok = (t == 0) ? 2 : tgt[b * 30 + (t - 1)];
  const float* src = emb + (size_t)tok * 512;
  short* dst = emb_all + ((size_t)t * 64 + b) * 512;
  int h = tid * 2;
  float a0 = src[h], a1 = src[h + 1];
  dst[h] = f2bf(a0); dst[h + 1] = f2bf(a1);
}

// ---------------------------------------------------------------- fprep: blocks 0-7 prep(t); blocks 8-71 finalize(t-1)
__global__ __launch_bounds__(256) void fprep_kernel(const short* __restrict__ xg_cur,
                                                    const short* __restrict__ wab,
                                                    float* __restrict__ qv,
                                                    const short* __restrict__ emb_all,
                                                    short* __restrict__ xg_w,
                                                    short* __restrict__ xf,
                                                    float* __restrict__ out, int t) {
  const int bid = blockIdx.x, tid = threadIdx.x;
  if (bid < 8) {
    const int wv = tid >> 6, lane = tid & 63;
    const int q = lane >> 4, ml = lane & 15;
    int n = bid * 64 + wv * 16 + ml;
    const f32x4 zz = {0.f, 0.f, 0.f, 0.f};
    f32x4 acc[4];
    acc[0] = zz; acc[1] = zz; acc[2] = zz; acc[3] = zz;
#pragma unroll
    for (int kt = 0; kt < 16; kt++) {       // K = 512 over hidden slot
      int k = kt * 32 + q * 8;
      s16x8 bfrag = *(const s16x8*)(wab + (size_t)n * 512 + k);
#pragma unroll
      for (int mt = 0; mt < 4; mt++) {
        s16x8 af = *(const s16x8*)(xg_cur + (size_t)(mt * 16 + ml) * 2048 + 1536 + k);
        acc[mt] = mfma16(af, bfrag, acc[mt]);
      }
    }
#pragma unroll
    for (int mt = 0; mt < 4; mt++)
#pragma unroll
      for (int r = 0; r < 4; r++)
        qv[(size_t)(mt * 16 + q * 4 + r) * 512 + n] = acc[mt][r];
    // embedding copy into xg/xf (precomputed bf16)
    int gid = bid * 256 + tid;              // [0,2048)
    int idx = gid * 16;                     // [0,32768)
    int b2 = idx >> 9, hh = idx & 511;
    const s16x8* src = (const s16x8*)(emb_all + (size_t)t * 32768 + idx);
    s16x8 e0 = src[0], e1 = src[1];
    *(s16x8*)(xg_w + (size_t)b2 * 2048 + hh) = e0;
    *(s16x8*)(xg_w + (size_t)b2 * 2048 + hh + 8) = e1;
    *(s16x8*)(xf + (size_t)b2 * 2048 + hh) = e0;
    *(s16x8*)(xf + (size_t)b2 * 2048 + hh + 8) = e1;
  } else if (t >= 1 && bid < 72) {
    // log_softmax of row (bid-8) at step t-1
    float* row = out + ((size_t)(bid - 8) * T_ + (t - 1)) * V_;
    __shared__ float red[256];
    float mx = -3.4e38f;
    for (int i = tid; i < 8000; i += 256) {
      f32x4 v = *(const f32x4*)(row + (size_t)i * 4);
      mx = fmaxf(mx, fmaxf(fmaxf(v[0], v[1]), fmaxf(v[2], v[3])));
    }
    red[tid] = mx; __syncthreads();
    for (int st = 128; st >= 1; st >>= 1) {
      if (tid < st) red[tid] = fmaxf(red[tid], red[tid + st]);
      __syncthreads();
    }
    mx = red[0]; __syncthreads();
    float sm = 0.f;
    for (int i = tid; i < 8000; i += 256) {
      f32x4 v = *(const f32x4*)(row + (size_t)i * 4);
      sm += __expf(v[0] - mx) + __expf(v[1] - mx) + __expf(v[2] - mx) + __expf(v[3] - mx);
    }
    red[tid] = sm; __syncthreads();
    for (int st = 128; st >= 1; st >>= 1) {
      if (tid < st) red[tid] += red[tid + st];
      __syncthreads();
    }
    float lse = mx + __logf(red[0]);
    for (int i = tid; i < 8000; i += 256) {
      f32x4 v = *(const f32x4*)(row + (size_t)i * 4);
      v[0] -= lse; v[1] -= lse; v[2] -= lse; v[3] -= lse;
      *(f32x4*)(row + (size_t)i * 4) = v;
    }
  }
}

// ---------------------------------------------------------------- standalone finalize (last step)
__global__ __launch_bounds__(256) void finalize_kernel(float* __restrict__ out, int t) {
  int b = blockIdx.x, tid = threadIdx.x;
  float* row = out + ((size_t)b * T_ + t) * V_;
  __shared__ float red[256];
  float mx = -3.4e38f;
  for (int i = tid; i < 8000; i += 256) {
    f32x4 v = *(const f32x4*)(row + (size_t)i * 4);
    mx = fmaxf(mx, fmaxf(fmaxf(v[0], v[1]), fmaxf(v[2], v[3])));
  }
  red[tid] = mx; __syncthreads();
  for (int st = 128; st >= 1; st >>= 1) {
    if (tid < st) red[tid] = fmaxf(red[tid], red[tid + st]);
    __syncthreads();
  }
  mx = red[0]; __syncthreads();
  float sm = 0.f;
  for (int i = tid; i < 8000; i += 256) {
    f32x4 v = *(const f32x4*)(row + (size_t)i * 4);
    sm += __expf(v[0] - mx) + __expf(v[1] - mx) + __expf(v[2] - mx) + __expf(v[3] - mx);
  }
  red[tid] = sm; __syncthreads();
  for (int st = 128; st >= 1; st >>= 1) {
    if (tid < st) red[tid] += red[tid + st];
    __syncthreads();
  }
  float lse = mx + __logf(red[0]);
  for (int i = tid; i < 8000; i += 256) {
    f32x4 v = *(const f32x4*)(row + (size_t)i * 4);
    v[0] -= lse; v[1] -= lse; v[2] -= lse; v[3] -= lse;
    *(f32x4*)(row + (size_t)i * 4) = v;
  }
}

// ---------------------------------------------------------------- fused attention: scores -> softmax -> context (grid 64)
template <bool ENCB>
__global__ __launch_bounds__(256) void attn_kernel(const float* __restrict__ qv,
                                                   const float* __restrict__ va,
                                                   const short* __restrict__ enc_ua,
                                                   const float* __restrict__ encf,
                                                   const short* __restrict__ encb,
                                                   short* __restrict__ xg_w,
                                                   short* __restrict__ xf) {
  __shared__ float q_s[512];
  __shared__ float va_s[512];
  __shared__ float p_s[128];
  __shared__ float red[128];
  const int b = blockIdx.x, tid = threadIdx.x;
  const int wv = tid >> 6, lane = tid & 63;
  for (int i = tid; i < 512; i += 256) {
    q_s[i] = qv[(size_t)b * 512 + i];
    va_s[i] = va[i];
  }
  __syncthreads();
  float qr[8], vr[8];
#pragma unroll
  for (int j = 0; j < 8; j++) { qr[j] = q_s[lane * 8 + j]; vr[j] = va_s[lane * 8 + j]; }
  for (int r = 0; r < 32; r++) {
    int s = wv * 32 + r;
    s16x8 e8 = *(const s16x8*)(enc_ua + ((size_t)b * 128 + s) * 512 + lane * 8);
    float a = 0.f;
#pragma unroll
    for (int j = 0; j < 8; j++) {
      float e = qr[j] + bf2f(e8[j]);
      float ex = __expf(2.f * e);
      a += (1.f - 2.f / (ex + 1.f)) * vr[j];
    }
#pragma unroll
    for (int off = 32; off > 0; off >>= 1) a += __shfl_down(a, off);
    if (lane == 0) p_s[s] = a;
  }
  __syncthreads();
  if (tid < 128) red[tid] = p_s[tid];
  __syncthreads();
  for (int st = 64; st >= 1; st >>= 1) {
    if (tid < st) red[tid] = fmaxf(red[tid], red[tid + st]);
    __syncthreads();
  }
  float mx = red[0]; __syncthreads();
  if (tid < 128) { float e = __expf(p_s[tid] - mx); p_s[tid] = e; red[tid] = e; }
  __syncthreads();
  for (int st = 64; st >= 1; st >>= 1) {
    if (tid < st) red[tid] += red[tid + st];
    __syncthreads();
  }
  float inv = 1.f / red[0]; __syncthreads();
  if (tid < 128) p_s[tid] *= inv;
  __syncthreads();
  int d4 = tid * 4;                         // [0,1024)
  f32x4 a = {0.f, 0.f, 0.f, 0.f};
  if (ENCB) {
    const short* ep = encb + (size_t)b * 128 * 1024 + d4;
#pragma unroll 4
    for (int s = 0; s < 128; s++) {
      s16x4 e = *(const s16x4*)(ep + (size_t)s * 1024);
      float p = p_s[s];
      a[0] += p * bf2f(e[0]); a[1] += p * bf2f(e[1]);
      a[2] += p * bf2f(e[2]); a[3] += p * bf2f(e[3]);
    }
  } else {
    const float* ep = encf + (size_t)b * 128 * 1024 + d4;
#pragma unroll 4
    for (int s = 0; s < 128; s++) {
      f32x4 e = *(const f32x4*)(ep + (size_t)s * 1024);
      float p = p_s[s];
      a[0] += p * e[0]; a[1] += p * e[1]; a[2] += p * e[2]; a[3] += p * e[3];
    }
  }
  s16x4 c4;
  c4[0] = f2bf(a[0]); c4[1] = f2bf(a[1]); c4[2] = f2bf(a[2]); c4[3] = f2bf(a[3]);
  *(s16x4*)(xg_w + (size_t)b * 2048 + 512 + d4) = c4;
  *(s16x4*)(xf + (size_t)b * 2048 + 1024 + d4) = c4;
}

// ---------------------------------------------------------------- fused GRU GEMM + gates (grid 32; 16 h-cols/block)
__global__ __launch_bounds__(256) void gru_kernel(const short* __restrict__ xg_cur,
                                                  const short* __restrict__ wihb,
                                                  const short* __restrict__ whhb,
                                                  const float* __restrict__ bih,
                                                  const float* __restrict__ bhh,
                                                  float* __restrict__ hidden,
                                                  short* __restrict__ xg_nxt,
                                                  short* __restrict__ xf) {
  __shared__ float gsm[12 * 64 * 17];       // 52.2 KB
  const int bid = blockIdx.x, tid = threadIdx.x;
  const int wv = tid >> 6, lane = tid & 63;
  const int q = lane >> 4, ml = lane & 15;
  const int c16 = bid * 16;
  const int c = c16 + ml;
  const f32x4 zz = {0.f, 0.f, 0.f, 0.f};
  f32x4 acc[3][4];
#pragma unroll
  for (int g = 0; g < 3; g++)
#pragma unroll
    for (int mt = 0; mt < 4; mt++) acc[g][mt] = zz;

  if (wv < 3) {                             // gi partial: K slice [wv*512, wv*512+512)
    const int kbase = wv * 512;
    for (int kt = 0; kt < 16; kt++) {
      int k = kbase + kt * 32 + q * 8;
      s16x8 af[4];
#pragma unroll
      for (int mt = 0; mt < 4; mt++)
        af[mt] = *(const s16x8*)(xg_cur + (size_t)(mt * 16 + ml) * 2048 + k);
#pragma unroll
      for (int g = 0; g < 3; g++) {
        s16x8 bf = *(const s16x8*)(wihb + (size_t)(g * 512 + c) * 1536 + k);
#pragma unroll
        for (int mt = 0; mt < 4; mt++) acc[g][mt] = mfma16(af[mt], bf, acc[g][mt]);
      }
    }
  } else {                                  // gh full: K=512 over hidden slot
    for (int kt = 0; kt < 16; kt++) {
      int k = kt * 32 + q * 8;
      s16x8 af[4];
#pragma unroll
      for (int mt = 0; mt < 4; mt++)
        af[mt] = *(const s16x8*)(xg_cur + (size_t)(mt * 16 + ml) * 2048 + 1536 + k);
#pragma unroll
      for (int g = 0; g < 3; g++) {
        s16x8 bf = *(const s16x8*)(whhb + (size_t)(g * 512 + c) * 512 + k);
#pragma unroll
        for (int mt = 0; mt < 4; mt++) acc[g][mt] = mfma16(af[mt], bf, acc[g][mt]);
      }
    }
  }
#pragma unroll
  for (int g = 0; g < 3; g++)
#pragma unroll
    for (int mt = 0; mt < 4; mt++)
#pragma unroll
      for (int r = 0; r < 4; r++)
        gsm[((wv * 3 + g) * 64 + mt * 16 + q * 4 + r) * 17 + ml] = acc[g][mt][r];
  __syncthreads();
#pragma unroll
  for (int j = 0; j < 4; j++) {
    int o = tid + j * 256;                  // 64 b x 16 c
    int cc = o & 15, bb = o >> 4;
    int hcol = c16 + cc;
    float gi0 = gsm[((0) * 64 + bb) * 17 + cc] + gsm[((3) * 64 + bb) * 17 + cc] + gsm[((6) * 64 + bb) * 17 + cc];
    float gi1 = gsm[((1) * 64 + bb) * 17 + cc] + gsm[((4) * 64 + bb) * 17 + cc] + gsm[((7) * 64 + bb) * 17 + cc];
    float gi2 = gsm[((2) * 64 + bb) * 17 + cc] + gsm[((5) * 64 + bb) * 17 + cc] + gsm[((8) * 64 + bb) * 17 + cc];
    float gh0 = gsm[((9) * 64 + bb) * 17 + cc];
    float gh1 = gsm[((10) * 64 + bb) * 17 + cc];
    float gh2 = gsm[((11) * 64 + bb) * 17 + cc];
    float ir = gi0 + bih[hcol],         hr = gh0 + bhh[hcol];
    float iz = gi1 + bih[512 + hcol],   hz = gh1 + bhh[512 + hcol];
    float in_ = gi2 + bih[1024 + hcol], hn = gh2 + bhh[1024 + hcol];
    float r = 1.f / (1.f + __expf(-(ir + hr)));
    float z = 1.f / (1.f + __expf(-(iz + hz)));
    float nx = in_ + r * hn;
    float ex = __expf(2.f * nx);
    float n = 1.f - 2.f / (ex + 1.f);
    float hold = hidden[(size_t)bb * 512 + hcol];
    float hnew = (1.f - z) * n + z * hold;
    hidden[(size_t)bb * 512 + hcol] = hnew;
    short hb = f2bf(hnew);
    xg_nxt[(size_t)bb * 2048 + 1536 + hcol] = hb;
    xf[(size_t)bb * 2048 + 512 + hcol] = hb;
  }
}

// ---------------------------------------------------------------- fc: logits = xf @ fc_w^T + fc_b  (250 blocks x 512 thr)
template <bool PRE>
__global__ __launch_bounds__(512) void fc_kernel(const short* __restrict__ xf,
                                                 const short* __restrict__ fcwb,
                                                 const float* __restrict__ fcwf,
                                                 const float* __restrict__ fcb,
                                                 float* __restrict__ out, int t) {
  __shared__ short alds[64 * 264];          // 33.8 KB
  const int tid = threadIdx.x;              // 0..511
  const int wv = tid >> 6, lane = tid & 63; // 8 waves
  const int q = lane >> 4, ml = lane & 15;
  const int n = blockIdx.x * 128 + wv * 16 + ml;
  const f32x4 zz = {0.f, 0.f, 0.f, 0.f};
  f32x4 acc[4];
  acc[0] = zz; acc[1] = zz; acc[2] = zz; acc[3] = zz;
  for (int kc = 0; kc < 8; kc++) {          // K chunks of 256
    __syncthreads();
    for (int i = tid; i < 2048; i += 512) { // 64 rows x 32 x (8 bf16)
      int m = i >> 5, kk = (i & 31) << 3;
      *(s16x8*)(&alds[m * 264 + kk]) = *(const s16x8*)(xf + (size_t)m * 2048 + kc * 256 + kk);
    }
    __syncthreads();
#pragma unroll
    for (int kt = 0; kt < 8; kt++) {
      int k = kt * 32 + q * 8;
      int gk = kc * 256 + k;
      s16x8 bf;
      if (PRE) {
        bf = *(const s16x8*)(fcwb + (size_t)n * 2048 + gk);
      } else {
        const float* p0 = fcwf + (size_t)n * 2048 + gk;
        f32x4 a0 = *(const f32x4*)p0, a1 = *(const f32x4*)(p0 + 4);
        bf[0] = f2bf(a0[0]); bf[1] = f2bf(a0[1]); bf[2] = f2bf(a0[2]); bf[3] = f2bf(a0[3]);
        bf[4] = f2bf(a1[0]); bf[5] = f2bf(a1[1]); bf[6] = f2bf(a1[2]); bf[7] = f2bf(a1[3]);
      }
#pragma unroll
      for (int mt = 0; mt < 4; mt++) {
        s16x8 af = *(const s16x8*)(&alds[(mt * 16 + ml) * 264 + k]);
        acc[mt] = mfma16(af, bf, acc[mt]);
      }
    }
  }
  float bias = fcb[n];
#pragma unroll
  for (int mt = 0; mt < 4; mt++)
#pragma unroll
    for (int r = 0; r < 4; r++) {
      int b = mt * 16 + q * 4 + r;
      out[((size_t)b * T_ + t) * V_ + n] = acc[mt][r] + bias;
    }
}

// ================================================================ host
extern "C" void kernel_launch(void* const* d_in, const int* in_sizes, int n_in,
                              void* d_out, int out_size, void* d_ws, size_t ws_size,
                              hipStream_t stream) {
  const float* enc  = (const float*)d_in[0];
  const float* ehid = (const float*)d_in[1];
  const int*   tgt  = (const int*)  d_in[2];
  const float* emb  = (const float*)d_in[3];
  const float* wa   = (const float*)d_in[4];
  const float* ua   = (const float*)d_in[5];
  const float* va   = (const float*)d_in[6];
  const float* wih  = (const float*)d_in[7];
  const float* whh  = (const float*)d_in[8];
  const float* bih  = (const float*)d_in[9];
  const float* bhh  = (const float*)d_in[10];
  const float* fcw  = (const float*)d_in[11];
  const float* fcb  = (const float*)d_in[12];
  float* out = (float*)d_out;

  const size_t SZ_FCWB = (size_t)V_ * KF_ * 2;        // 131 MB
  const size_t SZ_ENCB = (size_t)B_ * S_ * 1024 * 2;  // 16.8 MB
  char* ws = (char*)d_ws;
  size_t off = 0;
  auto take = [&](size_t bytes) -> char* {
    char* p = ws + off;
    off = (off + bytes + 255) & ~(size_t)255;
    return p;
  };
  size_t small_need;
  {
    size_t o = 0;
    auto sim = [&](size_t bb) { o = (o + bb + 255) & ~(size_t)255; };
    sim((size_t)B_ * S_ * H_ * 2);  // enc_ua bf16
    sim((size_t)3 * H_ * KX_ * 2);  // wihb
    sim((size_t)3 * H_ * H_ * 2);   // whhb
    sim((size_t)H_ * H_ * 2);       // wab
    sim((size_t)T_ * B_ * H_ * 2);  // emb_all
    sim((size_t)B_ * KF_ * 2);      // xg0
    sim((size_t)B_ * KF_ * 2);      // xg1
    sim((size_t)B_ * KF_ * 2);      // xf
    sim((size_t)B_ * H_ * 4);       // hidden
    sim((size_t)B_ * H_ * 4);       // qv
    small_need = o;
  }
  bool PRE  = ws_size >= SZ_FCWB + small_need + 512;
  bool ENCB = ws_size >= SZ_FCWB + SZ_ENCB + small_need + 1024;

  short* fcwb = PRE ? (short*)take(SZ_FCWB) : nullptr;
  short* encb = ENCB ? (short*)take(SZ_ENCB) : nullptr;
  short* enc_ua  = (short*)take((size_t)B_ * S_ * H_ * 2);
  short* wihb    = (short*)take((size_t)3 * H_ * KX_ * 2);
  short* whhb    = (short*)take((size_t)3 * H_ * H_ * 2);
  short* wab     = (short*)take((size_t)H_ * H_ * 2);
  short* emb_all = (short*)take((size_t)T_ * B_ * H_ * 2);
  short* xg0     = (short*)take((size_t)B_ * KF_ * 2);
  short* xg1     = (short*)take((size_t)B_ * KF_ * 2);
  short* xf      = (short*)take((size_t)B_ * KF_ * 2);
  float* hidden  = (float*)take((size_t)B_ * H_ * 4);
  float* qv      = (float*)take((size_t)B_ * H_ * 4);

  if (PRE)
    cvt_bf16_kernel<<<(V_ * KF_ / 4 + 255) / 256, 256, 0, stream>>>(fcw, fcwb, V_ * KF_ / 4);
  if (ENCB)
    cvt_bf16_kernel<<<(B_ * S_ * 1024 / 4 + 255) / 256, 256, 0, stream>>>(enc, encb, B_ * S_ * 1024 / 4);
  cvt_bf16_kernel<<<(3 * H_ * KX_ / 4 + 255) / 256, 256, 0, stream>>>(wih, wihb, 3 * H_ * KX_ / 4);
  cvt_bf16_kernel<<<(3 * H_ * H_ / 4 + 255) / 256, 256, 0, stream>>>(whh, whhb, 3 * H_ * H_ / 4);
  cvt_bf16_kernel<<<(H_ * H_ / 4 + 255) / 256, 256, 0, stream>>>(wa, wab, H_ * H_ / 4);
  init_kernel<<<(B_ * H_) / 256, 256, 0, stream>>>(ehid, hidden, xg0);
  enc_ua_kernel<<<dim3(128, 4), 256, 0, stream>>>(enc, ua, enc_ua);
  emb_gather_kernel<<<dim3(B_, T_), 256, 0, stream>>>(emb, tgt, emb_all);

  for (int t = 0; t < T_; t++) {
    short* xg_cur = (t & 1) ? xg1 : xg0;    // holds h(t-1) in slot 1536; emb/ctx of step t written here
    short* xg_nxt = (t & 1) ? xg0 : xg1;    // gru writes h(t) here for step t+1
    fprep_kernel<<<72, 256, 0, stream>>>(xg_cur, wab, qv, emb_all, xg_cur, xf, out, t);
    if (ENCB)
      attn_kernel<true><<<B_, 256, 0, stream>>>(qv, va, enc_ua, enc, encb, xg_cur, xf);
    else
      attn_kernel<false><<<B_, 256, 0, stream>>>(qv, va, enc_ua, enc, encb, xg_cur, xf);
    gru_kernel<<<32, 256, 0, stream>>>(xg_cur, wihb, whhb, bih, bhh, hidden, xg_nxt, xf);
    if (PRE)
      fc_kernel<true><<<V_ / 128, 512, 0, stream>>>(xf, fcwb, fcw, fcb, out, t);
    else
      fc_kernel<false><<<V_ / 128, 512, 0, stream>>>(xf, fcwb, fcw, fcb, out, t);
  }
  finalize_kernel<<<B_, 256, 0, stream>>>(out, T_ - 1);
}